// Round 5
// baseline (305.333 us; speedup 1.0000x reference)
//
#include <hip/hip_runtime.h>

typedef short bf16x8 __attribute__((ext_vector_type(8)));
typedef short short8 __attribute__((ext_vector_type(8)));
typedef float f32x16 __attribute__((ext_vector_type(16)));

#define DD 512
#define NG 512

typedef __attribute__((address_space(3))) void lds_void;
typedef __attribute__((address_space(1))) void glb_void;

static __device__ __forceinline__ void gload_lds16(const void* g, void* l) {
  __builtin_amdgcn_global_load_lds((const glb_void*)g, (lds_void*)l, 16, 0, 0);
}

#define WAITV(n) asm volatile("s_waitcnt vmcnt(" #n ") lgkmcnt(0)" ::: "memory")
#define MEMFENCE asm volatile("" ::: "memory")

// split f32 into bf16 hi (truncate) + bf16 lo (round) ; f ≈ hi + lo, ~2^-16 rel err
static __device__ __forceinline__ void cvt_hl(float f, unsigned short& h, unsigned short& l) {
  unsigned u = __builtin_bit_cast(unsigned, f);
  unsigned hu = u & 0xffff0000u;
  float fh = __builtin_bit_cast(float, hu);
  float fl = f - fh;                       // exact in f32
  unsigned ul = __builtin_bit_cast(unsigned, fl);
  h = (unsigned short)(hu >> 16);
  l = (unsigned short)((ul + 0x8000u) >> 16);
}

// fast tanh: 1 - 2/(e^{2v}+1), native exp/rcp (~1e-6 abs err, saturates correctly)
static __device__ __forceinline__ float fast_tanh(float v) {
  float e = __expf(2.0f * v);
  return 1.0f - 2.0f * __builtin_amdgcn_rcpf(e + 1.0f);
}

// Whl layout: [ny(2)][kt(32)][ct(8)][hl(2)][lane(64)=khalf*32+c31][e(8 bf16)]
// One (ny,kt) slice = 16 KB contiguous -> staged linearly by global_load_lds.
// B-fragment ds_read is lds + lane*16 (+ct*2048 +hl*1024): 64 lanes read 1024
// contiguous bytes -> zero bank conflicts (verified round 4: conflicts = 0).
__global__ __launch_bounds__(256) void k_convert_w(const float* __restrict__ W,
                                                   unsigned char* __restrict__ Whl) {
  int t = blockIdx.x * 256 + threadIdx.x;   // 32768 = 512 W-rows x 64 kgroups(8)
  int r512 = t >> 6, kg = t & 63;
  int ny = r512 >> 8, col = r512 & 255;
  int ct = col >> 5, c31 = col & 31;
  int kt = kg >> 1, khalf = kg & 1;
  const float* p = W + (size_t)r512 * DD + kg * 8;
  short8 h, l;
#pragma unroll
  for (int j = 0; j < 8; ++j) {
    unsigned short hh, ll;
    cvt_hl(p[j], hh, ll);
    h[j] = (short)hh;
    l[j] = (short)ll;
  }
  unsigned char* dst = Whl + (size_t)ny * 524288 + (size_t)kt * 16384 +
                       ct * 2048 + (khalf * 32 + c31) * 16;
  *(short8*)dst = h;             // hi plane
  *(short8*)(dst + 1024) = l;    // lo plane
}

// Fused GEMM(tanh-gate) + query-dot.  Wave = 32 rows x 128 cols (4 x 32x32x16
// tiles, 3 MFMAs each, acc = 64 regs).  Block = 4 waves = 64 rows x 256 cols
// (2 row-groups x 2 col-groups).  3 blocks/CU (LDS ring-3 = 48.5 KB, regs<=170).
// A prefetched one kt ahead in registers; B ring-3 staged, counted vmcnt.
__global__ __launch_bounds__(256, 3) void k_gemm_score(
    const float* __restrict__ x, const unsigned char* __restrict__ Whl,
    const float* __restrict__ bias, const float* __restrict__ query,
    float* __restrict__ score_part, int N) {
  __shared__ unsigned char lds[3][16384];
  __shared__ float comb[2][64];
  const int tid = threadIdx.x;
  const int wave = tid >> 6;
  const int lane = tid & 63;
  const int l31 = lane & 31;
  const int kh = lane >> 5;          // k-half within fragment
  const int rg = wave >> 1;          // row-group (0,1)
  const int cg = wave & 1;           // col-group (0,1)
  const int ny = blockIdx.x;
  const int row0 = blockIdx.y * 64 + rg * 32;

  const float* xp = x + (size_t)(row0 + l31) * DD + kh * 8;
  const unsigned char* wsrc = Whl + (size_t)ny * 524288 +
                              (size_t)wave * 4096 + (size_t)lane * 16;

  f32x16 acc[4];
#pragma unroll
  for (int j = 0; j < 4; ++j)
#pragma unroll
    for (int r = 0; r < 16; ++r) acc[j][r] = 0.f;

  // prologue: stage slice 0 | A(0) | stage slice 1   (fenced to pin vmcnt order)
#pragma unroll
  for (int i = 0; i < 4; ++i)
    gload_lds16(wsrc + i * 1024, &lds[0][wave * 4096 + i * 1024]);
  MEMFENCE;
  float4 a0 = *(const float4*)(xp);
  float4 a1 = *(const float4*)(xp + 4);
  MEMFENCE;
#pragma unroll
  for (int i = 0; i < 4; ++i)
    gload_lds16(wsrc + 16384 + i * 1024, &lds[1][wave * 4096 + i * 1024]);
  MEMFENCE;

  for (int kt = 0; kt < 32; ++kt) {
    // slice kt staged in body kt-2 (or prologue); 6 newer VMEM ops follow it
    // (A(kt) x2 + stage(kt+1) x4), so vmcnt(6) guarantees it landed.
    if (kt == 31) WAITV(2); else WAITV(6);
    __builtin_amdgcn_s_barrier();
    MEMFENCE;

    float4 n0, n1;
    if (kt < 31) {  // A-prefetch for kt+1 (issued BEFORE staging: cheaper dep-wait)
      n0 = *(const float4*)(xp + (kt + 1) * 16);
      n1 = *(const float4*)(xp + (kt + 1) * 16 + 4);
    }
    MEMFENCE;
    if (kt < 30) {  // stage slice kt+2; its slot's readers drained (lgkmcnt(0)+barrier)
      const unsigned char* src = wsrc + (size_t)(kt + 2) * 16384;
      unsigned char* dst = &lds[(kt + 2) % 3][wave * 4096];
#pragma unroll
      for (int i = 0; i < 4; ++i)
        gload_lds16(src + i * 1024, dst + i * 1024);
    }
    MEMFENCE;

    // convert A(kt) (prefetched last iteration) to bf16 hi/lo
    float af[8] = {a0.x, a0.y, a0.z, a0.w, a1.x, a1.y, a1.z, a1.w};
    bf16x8 ah, al;
#pragma unroll
    for (int j = 0; j < 8; ++j) {
      unsigned short hh, ll;
      cvt_hl(af[j], hh, ll);
      ah[j] = (short)hh;
      al[j] = (short)ll;
    }

    const unsigned char* bb = &lds[kt % 3][lane * 16];
#pragma unroll
    for (int j = 0; j < 4; ++j) {
      const int ct = cg * 4 + j;
      bf16x8 bh = *(const bf16x8*)(bb + ct * 2048);
      bf16x8 bl = *(const bf16x8*)(bb + ct * 2048 + 1024);
      acc[j] = __builtin_amdgcn_mfma_f32_32x32x16_bf16(ah, bh, acc[j], 0, 0, 0);
      acc[j] = __builtin_amdgcn_mfma_f32_32x32x16_bf16(al, bh, acc[j], 0, 0, 0);
      acc[j] = __builtin_amdgcn_mfma_f32_32x32x16_bf16(ah, bl, acc[j], 0, 0, 0);
    }
    a0 = n0;
    a1 = n1;
  }

  // epilogue: tanh + query-dot; reduce over the 32 col-lanes per C row
  float sp[16];
#pragma unroll
  for (int r = 0; r < 16; ++r) sp[r] = 0.f;
#pragma unroll
  for (int j = 0; j < 4; ++j) {
    const int col = ny * 256 + (cg * 4 + j) * 32 + l31;
    const float bb2 = bias[col];
    const float qq = query[col];
#pragma unroll
    for (int r = 0; r < 16; ++r)
      sp[r] += fast_tanh(acc[j][r] + bb2) * qq;
  }
  __syncthreads();   // safe to reuse LDS region (comb) now
#pragma unroll
  for (int r = 0; r < 16; ++r) {
    float v = sp[r];
    v += __shfl_xor(v, 1);
    v += __shfl_xor(v, 2);
    v += __shfl_xor(v, 4);
    v += __shfl_xor(v, 8);
    v += __shfl_xor(v, 16);
    if (l31 == 0)  // C row = (r&3) + 8*(r>>2) + 4*kh  (m74/m101 layout)
      comb[cg][rg * 32 + (r & 3) + 8 * (r >> 2) + 4 * kh] = v;
  }
  __syncthreads();
  if (tid < 64)
    score_part[(size_t)ny * N + blockIdx.y * 64 + tid] = comb[0][tid] + comb[1][tid];
}

// Per-graph: segmented softmax over (sp0+sp1) + weighted sum of x rows -> out[g][512]
__global__ __launch_bounds__(256) void k_softmax_out(
    const float* __restrict__ x, const void* __restrict__ segp,
    const float* __restrict__ sp0, const float* __restrict__ sp1,
    float* __restrict__ out, int N) {
  const int g = blockIdx.x;
  const int tid = threadIdx.x;

  // dtype probe: int64 element N/2-1 is a graph id (<NG) iff buffer is int64.
  const long long probe = ((const long long*)segp)[N / 2 - 1];
  const bool is64 = ((unsigned long long)probe < (unsigned long long)NG);
  const long long* s64 = (const long long*)segp;
  const int* s32 = (const int*)segp;

  int s0, s1;
  {
    int lo = 0, hi = N;
    while (lo < hi) {
      int m = (lo + hi) >> 1;
      long long v = is64 ? s64[m] : (long long)s32[m];
      if (v < (long long)g) lo = m + 1; else hi = m;
    }
    s0 = lo;
    lo = s0; hi = N;
    while (lo < hi) {
      int m = (lo + hi) >> 1;
      long long v = is64 ? s64[m] : (long long)s32[m];
      if (v < (long long)(g + 1)) lo = m + 1; else hi = m;
    }
    s1 = lo;
  }

  __shared__ float red[4];
  __shared__ float wbuf[512];

  float lm = -INFINITY;
  for (int i = s0 + tid; i < s1; i += 256) lm = fmaxf(lm, sp0[i] + sp1[i]);
#pragma unroll
  for (int m = 1; m < 64; m <<= 1) lm = fmaxf(lm, __shfl_xor(lm, m));
  if ((tid & 63) == 0) red[tid >> 6] = lm;
  __syncthreads();
  const float mx = fmaxf(fmaxf(red[0], red[1]), fmaxf(red[2], red[3]));
  __syncthreads();

  float ls = 0.f;
  for (int i = s0 + tid; i < s1; i += 256) ls += expf(sp0[i] + sp1[i] - mx);
#pragma unroll
  for (int m = 1; m < 64; m <<= 1) ls += __shfl_xor(ls, m);
  if ((tid & 63) == 0) red[tid >> 6] = ls;
  __syncthreads();
  const float sum = red[0] + red[1] + red[2] + red[3];
  const float inv = sum > 0.f ? 1.0f / sum : 0.f;

  float a0 = 0.f, a1 = 0.f;
  const int c = tid * 2;
  for (int base = s0; base < s1; base += 512) {
    const int cnt = min(512, s1 - base);
    __syncthreads();
    for (int i = tid; i < cnt; i += 256)
      wbuf[i] = expf(sp0[base + i] + sp1[base + i] - mx) * inv;
    __syncthreads();
#pragma unroll 4
    for (int j = 0; j < cnt; ++j) {
      const float w = wbuf[j];
      const float2 xv = *(const float2*)(x + (size_t)(base + j) * DD + c);
      a0 = fmaf(w, xv.x, a0);
      a1 = fmaf(w, xv.y, a1);
    }
  }
  float* op = out + (size_t)g * DD + c;
  op[0] = a0;
  op[1] = a1;
}

extern "C" void kernel_launch(void* const* d_in, const int* in_sizes, int n_in,
                              void* d_out, int out_size, void* d_ws, size_t ws_size,
                              hipStream_t stream) {
  const float* x = (const float*)d_in[0];
  const void* seg = d_in[1];
  const float* W = (const float*)d_in[2];
  const float* b = (const float*)d_in[3];
  const float* q = (const float*)d_in[4];
  float* out = (float*)d_out;
  const int N = in_sizes[0] / DD;  // 131072

  unsigned char* Whl = (unsigned char*)d_ws;                 // 1 MB packed W (hi/lo)
  float* sp0 = (float*)(Whl + 1048576);                      // N partial scores (ny=0)
  float* sp1 = sp0 + N;                                      // N partial scores (ny=1)

  k_convert_w<<<128, 256, 0, stream>>>(W, Whl);
  dim3 grid(2, N / 64);                                      // x = ny fastest -> x-row cache reuse
  k_gemm_score<<<grid, 256, 0, stream>>>(x, Whl, b, q, sp0, N);
  k_softmax_out<<<NG, 256, 0, stream>>>(x, seg, sp0, sp1, out, N);
}

// Round 6
// 267.641 us; speedup vs baseline: 1.1408x; 1.1408x over previous
//
#include <hip/hip_runtime.h>

typedef short bf16x8 __attribute__((ext_vector_type(8)));
typedef short short8 __attribute__((ext_vector_type(8)));
typedef float f32x16 __attribute__((ext_vector_type(16)));

#define DD 512
#define NG 512

typedef __attribute__((address_space(3))) void lds_void;
typedef __attribute__((address_space(1))) void glb_void;

static __device__ __forceinline__ void gload_lds16(const void* g, void* l) {
  __builtin_amdgcn_global_load_lds((const glb_void*)g, (lds_void*)l, 16, 0, 0);
}

#define WAITV(n) asm volatile("s_waitcnt vmcnt(" #n ") lgkmcnt(0)" ::: "memory")
#define MEMFENCE asm volatile("" ::: "memory")

// split f32 into bf16 hi (truncate) + bf16 lo (round) ; f ≈ hi + lo, ~2^-16 rel err
static __device__ __forceinline__ void cvt_hl(float f, unsigned short& h, unsigned short& l) {
  unsigned u = __builtin_bit_cast(unsigned, f);
  unsigned hu = u & 0xffff0000u;
  float fh = __builtin_bit_cast(float, hu);
  float fl = f - fh;                       // exact in f32
  unsigned ul = __builtin_bit_cast(unsigned, fl);
  h = (unsigned short)(hu >> 16);
  l = (unsigned short)((ul + 0x8000u) >> 16);
}

// fast tanh: 1 - 2/(e^{2v}+1), native exp/rcp (~1e-6 abs err, saturates correctly)
static __device__ __forceinline__ float fast_tanh(float v) {
  float e = __expf(2.0f * v);
  return 1.0f - 2.0f * __builtin_amdgcn_rcpf(e + 1.0f);
}

// Whl layout: [ny(2)][kt(32)][ct(8)][hl(2)][lane(64)=khalf*32+c31][e(8 bf16)]
// One (ny,kt) slice = 16 KB contiguous -> staged linearly by global_load_lds.
// B-fragment ds_read is lds + lane*16 (+ct*2048 +hl*1024): 64 lanes read 1024
// contiguous bytes -> zero bank conflicts (verified round 4: conflicts = 0).
__global__ __launch_bounds__(256) void k_convert_w(const float* __restrict__ W,
                                                   unsigned char* __restrict__ Whl) {
  int t = blockIdx.x * 256 + threadIdx.x;   // 32768 = 512 W-rows x 64 kgroups(8)
  int r512 = t >> 6, kg = t & 63;
  int ny = r512 >> 8, col = r512 & 255;
  int ct = col >> 5, c31 = col & 31;
  int kt = kg >> 1, khalf = kg & 1;
  const float* p = W + (size_t)r512 * DD + kg * 8;
  short8 h, l;
#pragma unroll
  for (int j = 0; j < 8; ++j) {
    unsigned short hh, ll;
    cvt_hl(p[j], hh, ll);
    h[j] = (short)hh;
    l[j] = (short)ll;
  }
  unsigned char* dst = Whl + (size_t)ny * 524288 + (size_t)kt * 16384 +
                       ct * 2048 + (khalf * 32 + c31) * 16;
  *(short8*)dst = h;             // hi plane
  *(short8*)(dst + 1024) = l;    // lo plane
}

// Fused GEMM(tanh-gate) + query-dot.  Block = 4 waves x (32 rows x 256 cols)
// = 128 rows x 256 cols (ny = col half).  ALL loop operands staged via
// global_load_lds ring-3 with counted vmcnt: B slices (16 KB) + A x-tiles
// (8 KB, gathered per-lane from row-major x).  72.5 KB LDS -> 2 blocks/CU.
// No HBM->VGPR loads in the K-loop; setprio(1) around the MFMA cluster.
__global__ __launch_bounds__(256, 2) void k_gemm_score(
    const float* __restrict__ x, const unsigned char* __restrict__ Whl,
    const float* __restrict__ bias, const float* __restrict__ query,
    float* __restrict__ score_part, int N) {
  __shared__ unsigned char ldsB[3][16384];
  __shared__ unsigned char ldsA[3][8192];
  const int tid = threadIdx.x;
  const int wave = tid >> 6;
  const int lane = tid & 63;
  const int l31 = lane & 31;
  const int kh = lane >> 5;          // k-half within fragment
  const int ny = blockIdx.x;
  const int brow0 = blockIdx.y * 128;
  const int row0 = brow0 + wave * 32;

  const unsigned char* wsrc = Whl + (size_t)ny * 524288 +
                              (size_t)wave * 4096 + (size_t)lane * 16;
  // A gather: chunk = wave*128 + i*64 + lane; row = chunk>>2, kq = chunk&3
  const int ch0 = wave * 128 + lane;
  const float* asrc0 = x + (size_t)(brow0 + (ch0 >> 2)) * DD + (ch0 & 3) * 4;
  const int ch1 = ch0 + 64;
  const float* asrc1 = x + (size_t)(brow0 + (ch1 >> 2)) * DD + (ch1 & 3) * 4;

  f32x16 acc[8];
#pragma unroll
  for (int ct = 0; ct < 8; ++ct)
#pragma unroll
    for (int r = 0; r < 16; ++r) acc[ct][r] = 0.f;

  // prologue: stage slices 0 and 1 (6 gloads each: 4 B + 2 A, fenced in order)
#pragma unroll
  for (int s = 0; s < 2; ++s) {
#pragma unroll
    for (int i = 0; i < 4; ++i)
      gload_lds16(wsrc + (size_t)s * 16384 + i * 1024, &ldsB[s][wave * 4096 + i * 1024]);
    gload_lds16(asrc0 + s * 16, &ldsA[s][wave * 2048]);
    gload_lds16(asrc1 + s * 16, &ldsA[s][wave * 2048 + 1024]);
    MEMFENCE;
  }

  for (int kt = 0; kt < 32; ++kt) {
    // slice kt's 6 gloads have exactly {kt+1}'s 6 newer -> vmcnt(6); tail drains.
    if (kt == 31) WAITV(0); else WAITV(6);
    __builtin_amdgcn_s_barrier();
    MEMFENCE;

    if (kt < 30) {  // stage slice kt+2 into slot (kt+2)%3 (readers of kt-1 done)
      const int s = (kt + 2) % 3;
      const unsigned char* src = wsrc + (size_t)(kt + 2) * 16384;
#pragma unroll
      for (int i = 0; i < 4; ++i)
        gload_lds16(src + i * 1024, &ldsB[s][wave * 4096 + i * 1024]);
      gload_lds16(asrc0 + (kt + 2) * 16, &ldsA[s][wave * 2048]);
      gload_lds16(asrc1 + (kt + 2) * 16, &ldsA[s][wave * 2048 + 1024]);
    }
    MEMFENCE;

    const int slot = kt % 3;
    // A fragment from LDS: row l31 (this wave's 32-row slice), k-half kh
    const unsigned char* aa = &ldsA[slot][(wave * 32 + l31) * 64 + kh * 32];
    const float4 a0 = *(const float4*)(aa);
    const float4 a1 = *(const float4*)(aa + 16);
    float af[8] = {a0.x, a0.y, a0.z, a0.w, a1.x, a1.y, a1.z, a1.w};
    bf16x8 ah, al;
#pragma unroll
    for (int j = 0; j < 8; ++j) {
      unsigned short hh, ll;
      cvt_hl(af[j], hh, ll);
      ah[j] = (short)hh;
      al[j] = (short)ll;
    }

    const unsigned char* bb = &ldsB[slot][lane * 16];
    __builtin_amdgcn_s_setprio(1);
#pragma unroll
    for (int ct = 0; ct < 8; ++ct) {
      bf16x8 bh = *(const bf16x8*)(bb + ct * 2048);
      bf16x8 bl = *(const bf16x8*)(bb + ct * 2048 + 1024);
      acc[ct] = __builtin_amdgcn_mfma_f32_32x32x16_bf16(ah, bh, acc[ct], 0, 0, 0);
      acc[ct] = __builtin_amdgcn_mfma_f32_32x32x16_bf16(al, bh, acc[ct], 0, 0, 0);
      acc[ct] = __builtin_amdgcn_mfma_f32_32x32x16_bf16(ah, bl, acc[ct], 0, 0, 0);
    }
    __builtin_amdgcn_s_setprio(0);
  }

  // epilogue: tanh + query-dot; reduce over the 32 col-lanes per C row
  float sp[16];
#pragma unroll
  for (int r = 0; r < 16; ++r) sp[r] = 0.f;
#pragma unroll
  for (int ct = 0; ct < 8; ++ct) {
    const int col = ny * 256 + ct * 32 + l31;
    const float bb2 = bias[col];
    const float qq = query[col];
#pragma unroll
    for (int r = 0; r < 16; ++r)
      sp[r] += fast_tanh(acc[ct][r] + bb2) * qq;
  }
#pragma unroll
  for (int r = 0; r < 16; ++r) {
    float v = sp[r];
    v += __shfl_xor(v, 1);
    v += __shfl_xor(v, 2);
    v += __shfl_xor(v, 4);
    v += __shfl_xor(v, 8);
    v += __shfl_xor(v, 16);
    if (l31 == 0)  // C row = (r&3) + 8*(r>>2) + 4*kh  (m74/m101 layout)
      score_part[(size_t)ny * N + row0 + (r & 3) + 8 * (r >> 2) + 4 * kh] = v;
  }
}

// Per-graph: segmented softmax over (sp0+sp1) + weighted sum of x rows -> out[g][512]
__global__ __launch_bounds__(256) void k_softmax_out(
    const float* __restrict__ x, const void* __restrict__ segp,
    const float* __restrict__ sp0, const float* __restrict__ sp1,
    float* __restrict__ out, int N) {
  const int g = blockIdx.x;
  const int tid = threadIdx.x;

  // dtype probe: int64 element N/2-1 is a graph id (<NG) iff buffer is int64.
  const long long probe = ((const long long*)segp)[N / 2 - 1];
  const bool is64 = ((unsigned long long)probe < (unsigned long long)NG);
  const long long* s64 = (const long long*)segp;
  const int* s32 = (const int*)segp;

  int s0, s1;
  {
    int lo = 0, hi = N;
    while (lo < hi) {
      int m = (lo + hi) >> 1;
      long long v = is64 ? s64[m] : (long long)s32[m];
      if (v < (long long)g) lo = m + 1; else hi = m;
    }
    s0 = lo;
    lo = s0; hi = N;
    while (lo < hi) {
      int m = (lo + hi) >> 1;
      long long v = is64 ? s64[m] : (long long)s32[m];
      if (v < (long long)(g + 1)) lo = m + 1; else hi = m;
    }
    s1 = lo;
  }

  __shared__ float red[4];
  __shared__ float wbuf[512];

  float lm = -INFINITY;
  for (int i = s0 + tid; i < s1; i += 256) lm = fmaxf(lm, sp0[i] + sp1[i]);
#pragma unroll
  for (int m = 1; m < 64; m <<= 1) lm = fmaxf(lm, __shfl_xor(lm, m));
  if ((tid & 63) == 0) red[tid >> 6] = lm;
  __syncthreads();
  const float mx = fmaxf(fmaxf(red[0], red[1]), fmaxf(red[2], red[3]));
  __syncthreads();

  float ls = 0.f;
  for (int i = s0 + tid; i < s1; i += 256) ls += expf(sp0[i] + sp1[i] - mx);
#pragma unroll
  for (int m = 1; m < 64; m <<= 1) ls += __shfl_xor(ls, m);
  if ((tid & 63) == 0) red[tid >> 6] = ls;
  __syncthreads();
  const float sum = red[0] + red[1] + red[2] + red[3];
  const float inv = sum > 0.f ? 1.0f / sum : 0.f;

  float a0 = 0.f, a1 = 0.f;
  const int c = tid * 2;
  for (int base = s0; base < s1; base += 512) {
    const int cnt = min(512, s1 - base);
    __syncthreads();
    for (int i = tid; i < cnt; i += 256)
      wbuf[i] = expf(sp0[base + i] + sp1[base + i] - mx) * inv;
    __syncthreads();
#pragma unroll 4
    for (int j = 0; j < cnt; ++j) {
      const float w = wbuf[j];
      const float2 xv = *(const float2*)(x + (size_t)(base + j) * DD + c);
      a0 = fmaf(w, xv.x, a0);
      a1 = fmaf(w, xv.y, a1);
    }
  }
  float* op = out + (size_t)g * DD + c;
  op[0] = a0;
  op[1] = a1;
}

extern "C" void kernel_launch(void* const* d_in, const int* in_sizes, int n_in,
                              void* d_out, int out_size, void* d_ws, size_t ws_size,
                              hipStream_t stream) {
  const float* x = (const float*)d_in[0];
  const void* seg = d_in[1];
  const float* W = (const float*)d_in[2];
  const float* b = (const float*)d_in[3];
  const float* q = (const float*)d_in[4];
  float* out = (float*)d_out;
  const int N = in_sizes[0] / DD;  // 131072

  unsigned char* Whl = (unsigned char*)d_ws;                 // 1 MB packed W (hi/lo)
  float* sp0 = (float*)(Whl + 1048576);                      // N partial scores (ny=0)
  float* sp1 = sp0 + N;                                      // N partial scores (ny=1)

  k_convert_w<<<128, 256, 0, stream>>>(W, Whl);
  dim3 grid(2, N / 128);                                     // x = ny fastest -> x-row cache reuse
  k_gemm_score<<<grid, 256, 0, stream>>>(x, Whl, b, q, sp0, N);
  k_softmax_out<<<NG, 256, 0, stream>>>(x, seg, sp0, sp1, out, N);
}